// Round 19
// baseline (49.673 us; speedup 1.0000x reference)
//
#include <hip/hip_runtime.h>
#include <math.h>

// NeRF fused volume renderer, MI355X (gfx950) — MFMA, independent-wave design.
// Round 19: r17/r18 base + TWO-TILE ILP per wave.
//   r17/r18 isolated the limiter: per-tile serial chain (~700cy) at 46% VALU /
//   11% MFMA — neither pipe saturated, TLP capped by LDS/VGPR tiers. Fix:
//   process tile PAIRS (2bp, 2bp+1): the two MLPs are independent (f-carry
//   applies only at compositing), every weight/bias/pdf LDS load is SHARED,
//   and the interleaved MFMA/VALU chains give each wave ~2x issue parallelism.
//   Empty tiles stay exact via the per-lane valid mask (sigma=0 -> f unchanged).
//   Natural VGPR allocation (no bounds hint) — expect ~100 VGPR clean,
//   5 waves/SIMD; effective concurrency ~40 tile-pipelines/CU.
//   Kept from r17/r18: scalarized wave-uniform setup (rfl->SGPR), wave=ray with
//   sequential tile pairs, 6-register carry, zero main-loop barriers.
// Layouts (m89-verified / ISA doc): C/D col=lane&15, row=(lane>>4)*4+reg;
// x32 A/B k=(lane>>4)*8+e; x16 A/B k=(lane>>4)*4+e.

typedef _Float16 f16x8 __attribute__((ext_vector_type(8)));
typedef _Float16 f16x4 __attribute__((ext_vector_type(4)));
typedef float f32x4 __attribute__((ext_vector_type(4)));

static constexpr float STEPf = 0.040594940802395566f; // 3*sqrt(3)/128 in f32

static __device__ __forceinline__ unsigned pk2(float a, float b) {
    return __builtin_bit_cast(unsigned, __builtin_amdgcn_cvt_pkrtz(a, b));
}
static __device__ __forceinline__ f16x8 mk8(unsigned a, unsigned b, unsigned c, unsigned d) {
    uint4 u = make_uint4(a, b, c, d);
    return __builtin_bit_cast(f16x8, u);
}
static __device__ __forceinline__ f16x4 pkh(const f32x4 c) {
    uint2 u;
    u.x = pk2(fmaxf(c[0], 0.f), fmaxf(c[1], 0.f));
    u.y = pk2(fmaxf(c[2], 0.f), fmaxf(c[3], 0.f));
    return __builtin_bit_cast(f16x4, u);
}
static __device__ __forceinline__ float rfl(float x) {
    return __builtin_bit_cast(float, __builtin_amdgcn_readfirstlane(__builtin_bit_cast(int, x)));
}

extern "C" __global__ void __launch_bounds__(256)
nerf_mfma(const float* __restrict__ rays_o, const float* __restrict__ viewdirs,
          const void* __restrict__ occ,
          const float* __restrict__ W1g, const float* __restrict__ b1g,
          const float* __restrict__ W2g, const float* __restrict__ b2g,
          const float* __restrict__ Wsg, const float* __restrict__ bsg,
          const float* __restrict__ Wcg, const float* __restrict__ Wdg,
          const float* __restrict__ bcg, const float* __restrict__ Wrg,
          const float* __restrict__ brg,
          float* __restrict__ out, int nrays)
{
    __shared__ __align__(16) unsigned char sW1[64 * 64];
    __shared__ __align__(16) unsigned char sW2[64 * 128];
    __shared__ __align__(16) unsigned char sWc[64 * 128];
    __shared__ __align__(16) unsigned char sHC[16 * 128];
    __shared__ __align__(16) float sWs[64];
    __shared__ __align__(16) float sB1[64], sB2[64];
    __shared__ __align__(16) float sPdB[4][64];    // per-wave (pe_d@Wd + bc); same-wave RW
    __shared__ int sKind;

    const int tid = threadIdx.x;   // 0..255

    // ---------------- staging: COALESCED global reads, swizzled LDS writes ----
    for (int idx = tid; idx < 1024; idx += 256)             // zero sW1 (covers k-pad)
        ((uint32_t*)sW1)[idx] = 0u;
    __syncthreads();                                        // pad-zero before scatter
    for (int idx = tid; idx < 27 * 64; idx += 256) {        // W1, linear in memory
        const int k = idx >> 6, h = idx & 63;
        *(_Float16*)(sW1 + h * 64 + (((k >> 3) ^ (h & 3)) << 4) + ((k & 7) << 1)) =
            (_Float16)W1g[idx];
    }
    for (int idx = tid; idx < 64 * 64; idx += 256) {        // W2, Wc, linear
        const int k = idx >> 6, h = idx & 63;
        const int off = h * 128 + ((((k >> 2) ^ ((h & 7) << 1)) << 3)) + ((k & 3) << 1);
        *(_Float16*)(sW2 + off) = (_Float16)W2g[idx];
        *(_Float16*)(sWc + off) = (_Float16)Wcg[idx];
    }
    for (int idx = tid; idx < 192; idx += 256) {            // rgb head rows, linear
        const int kk = idx / 3, c = idx - 3 * kk;
        const _Float16 v = (_Float16)Wrg[idx];
        #pragma unroll
        for (int r = 0; r < 16; ++r) {
            if ((r % 3) == c) {
                const int off = r * 128 + ((((kk >> 2) ^ ((r & 7) << 1)) << 3)) + ((kk & 3) << 1);
                *(_Float16*)(sHC + off) = v;
            }
        }
    }
    if (tid < 64) {
        sB1[tid] = b1g[tid]; sB2[tid] = b2g[tid];
        sWs[tid] = Wsg[tid];
    }
    if (tid == 0) {   // sniff occ dtype: 0=u8, else 32-bit raw (i32/f32 both !=0 test)
        const int*   oi = (const int*)occ;
        const float* of = (const float*)occ;
        bool i32ok = true, f32ok = true;
        for (int k = 0; k < 64; ++k) {
            if (oi[k] != 0 && oi[k] != 1) i32ok = false;
            const float f = of[k];
            if (!(f == 0.f || f == 1.f)) f32ok = false;
        }
        sKind = (i32ok || f32ok) ? 1 : 0;
    }
    __syncthreads();   // the ONLY block-wide barrier

    const int lane = tid & 63;
    const int wid  = tid >> 6;        // 0..3: wave = independent ray
    const int kind = sKind;
    const int lh = lane & 15, g = lane >> 4;
    const int swz8 = (lh & 7) << 1;

    const float bsV = bsg[0];
    const float br0 = brg[0], br1 = brg[1], br2 = brg[2];

    const int ray = __builtin_amdgcn_readfirstlane((int)(blockIdx.x << 2) + wid);
    if (ray >= nrays) return;

    // ---- per-ray setup; uniform scalars end in SGPRs (scalar loads + rfl) ----
    const float ox = rays_o[ray * 3 + 0], oy = rays_o[ray * 3 + 1], oz = rays_o[ray * 3 + 2];
    const float dxv = viewdirs[ray * 3 + 0], dyv = viewdirs[ray * 3 + 1], dzv = viewdirs[ray * 3 + 2];
    float t_near, t_far;
    {
        const float sdx = fabsf(dxv) < 1e-8f ? 1e-8f : dxv;
        const float sdy = fabsf(dyv) < 1e-8f ? 1e-8f : dyv;
        const float sdz = fabsf(dzv) < 1e-8f ? 1e-8f : dzv;
        const float t1x = (-1.5f - ox) / sdx, t2x = (1.5f - ox) / sdx;
        const float t1y = (-1.5f - oy) / sdy, t2y = (1.5f - oy) / sdy;
        const float t1z = (-1.5f - oz) / sdz, t2z = (1.5f - oz) / sdz;
        t_near = rfl(fmaxf(fmaxf(fminf(t1x, t2x), fminf(t1y, t2y)),
                           fmaxf(fminf(t1z, t2z), 0.f)));
        t_far  = rfl(fminf(fminf(fmaxf(t1x, t2x), fmaxf(t1y, t2y)), fmaxf(t1z, t2z)));
    }

    float W = 0.f, WT = 0.f, Rr = 0.f, Gg = 0.f, Bb = 0.f;

    if (t_near < t_far) {
        // dir posenc -> sPdB[wid] (lane j computes feature j; same-wave RW)
        {
            float ped[15];
            ped[0] = dxv; ped[1] = dyv; ped[2] = dzv;
            const float dc[3] = {dxv, dyv, dzv};
            #pragma unroll
            for (int c = 0; c < 3; ++c) {
                float s1, c1;
                __sincosf(dc[c], &s1, &c1);
                ped[3 + c * 4 + 0] = s1;
                ped[3 + c * 4 + 1] = 2.f * s1 * c1;
                ped[3 + c * 4 + 2] = c1;
                ped[3 + c * 4 + 3] = 1.f - 2.f * s1 * s1;
            }
            float pd = 0.f;
            #pragma unroll
            for (int i = 0; i < 15; ++i) pd += ped[i] * Wdg[i * 64 + lane];
            sPdB[wid][lane] = pd + bcg[lane];
        }

        // sample validity for a given t (own sample of this lane)
        auto validAt = [&](float t, bool inseg) -> bool {
            const float px = ox + dxv * t, py = oy + dyv * t, pz = oz + dzv * t;
            const float cx = (px + 1.5f) * (128.f / 3.f);
            const float cy = (py + 1.5f) * (128.f / 3.f);
            const float cz = (pz + 1.5f) * (128.f / 3.f);
            const bool in_box = (cx >= 0.f) & (cx < 128.f) & (cy >= 0.f) & (cy < 128.f)
                              & (cz >= 0.f) & (cz < 128.f);
            const int ix = min(max((int)floorf(cx), 0), 127);
            const int iy = min(max((int)floorf(cy), 0), 127);
            const int iz = min(max((int)floorf(cz), 0), 127);
            const int ci = (ix << 14) | (iy << 7) | iz;
            const unsigned raw = (kind == 0) ? (unsigned)((const unsigned char*)occ)[ci]
                                             : ((const unsigned*)occ)[ci];
            return inseg & in_box & (raw != 0u);
        };
        // posenc in x32-B layout for a given t
        auto posenc = [&](float t) -> f16x8 {
            const float qx = ox + dxv * t, qy = oy + dyv * t, qz = oz + dzv * t;
            const float u = (g < 2) ? qx : ((g == 2) ? qy : qz);
            const float v = (g == 1) ? qy : ((g == 2) ? qz : 0.f);
            float su1, cu1, sv1, cv1;
            __sincosf(u, &su1, &cu1);
            __sincosf(v, &sv1, &cv1);
            const float su2 = 2.f * su1 * cu1, cu2 = 1.f - 2.f * su1 * su1;
            const float su4 = 2.f * su2 * cu2, cu4 = 1.f - 2.f * su2 * su2;
            const float su8 = 2.f * su4 * cu4, cu8 = 1.f - 2.f * su4 * su4;
            const float sv2 = 2.f * sv1 * cv1, cv2 = 1.f - 2.f * sv1 * sv1;
            const float sv4 = 2.f * sv2 * cv2, cv4 = 1.f - 2.f * sv2 * sv2;
            const float sv8 = 2.f * sv4 * cv4;
            const bool g0 = (g == 0);
            const float f0 = g0 ? qx : cu2;
            const float f1 = g0 ? qy : cu4;
            const float f2 = g0 ? qz : cu8;
            const float f3 = g0 ? su1 : sv1;
            const float f4 = g0 ? su2 : sv2;
            const float f5 = g0 ? su4 : sv4;
            const float f6 = g0 ? su8 : sv8;
            const float f7 = g0 ? cu1 : ((g == 3) ? 0.f : cv1);
            return mk8(pk2(f0, f1), pk2(f2, f3), pk2(f4, f5), pk2(f6, f7));
        };

        float f = 1.f;
        #pragma unroll 1
        for (int bp = 0; bp < 4; ++bp) {
            const float tA = t_near + ((float)((bp << 5) | lh) + 0.5f) * STEPf;
            const float tB = tA + 16.f * STEPf;
            const bool insegA = tA < t_far;
            const bool insegB = tB < t_far;
            if (__ballot(insegA) == 0ULL) break;   // tiles ascend in t: done

            const bool validA = validAt(tA, insegA);
            const bool validB = validAt(tB, insegB);

            if (__ballot(validA | validB) != 0ULL) {
                const f16x8 bxA = posenc(tA);
                const f16x8 bxB = posenc(tB);

                // ---- L1 (16x16x32): shared A-fragment, two MFMAs ----
                f16x4 bh1A[4], bh1B[4];
                #pragma unroll
                for (int mt = 0; mt < 4; ++mt) {
                    const f32x4 bf = *(const f32x4*)&sB1[16 * mt + 4 * g];
                    const f16x8 a = *(const f16x8*)(sW1 + (16 * mt + lh) * 64 + ((g ^ (lh & 3)) << 4));
                    f32x4 cA = __builtin_amdgcn_mfma_f32_16x16x32_f16(a, bxA, bf, 0, 0, 0);
                    f32x4 cB = __builtin_amdgcn_mfma_f32_16x16x32_f16(a, bxB, bf, 0, 0, 0);
                    bh1A[mt] = pkh(cA);
                    bh1B[mt] = pkh(cB);
                }
                // ---- L2 (x16 chains) + fused sigma partials, shared weight loads ----
                f16x4 bh2A[4], bh2B[4];
                float spA = 0.f, spB = 0.f;
                #pragma unroll
                for (int mt = 0; mt < 4; ++mt) {
                    const int row = (16 * mt + lh) * 128;
                    const f16x4 a0 = *(const f16x4*)(sW2 + row + (((0 + g) ^ swz8) << 3));
                    const f16x4 a1 = *(const f16x4*)(sW2 + row + (((4 + g) ^ swz8) << 3));
                    const f16x4 a2 = *(const f16x4*)(sW2 + row + (((8 + g) ^ swz8) << 3));
                    const f16x4 a3 = *(const f16x4*)(sW2 + row + (((12 + g) ^ swz8) << 3));
                    const f32x4 bf = *(const f32x4*)&sB2[16 * mt + 4 * g];
                    const f32x4 ws = *(const f32x4*)&sWs[16 * mt + 4 * g];
                    f32x4 cA = __builtin_amdgcn_mfma_f32_16x16x16f16(a0, bh1A[0], bf, 0, 0, 0);
                    f32x4 cB = __builtin_amdgcn_mfma_f32_16x16x16f16(a0, bh1B[0], bf, 0, 0, 0);
                    cA = __builtin_amdgcn_mfma_f32_16x16x16f16(a1, bh1A[1], cA, 0, 0, 0);
                    cB = __builtin_amdgcn_mfma_f32_16x16x16f16(a1, bh1B[1], cB, 0, 0, 0);
                    cA = __builtin_amdgcn_mfma_f32_16x16x16f16(a2, bh1A[2], cA, 0, 0, 0);
                    cB = __builtin_amdgcn_mfma_f32_16x16x16f16(a2, bh1B[2], cB, 0, 0, 0);
                    cA = __builtin_amdgcn_mfma_f32_16x16x16f16(a3, bh1A[3], cA, 0, 0, 0);
                    cB = __builtin_amdgcn_mfma_f32_16x16x16f16(a3, bh1B[3], cB, 0, 0, 0);
                    const float rA0 = fmaxf(cA[0], 0.f), rA1 = fmaxf(cA[1], 0.f);
                    const float rA2 = fmaxf(cA[2], 0.f), rA3 = fmaxf(cA[3], 0.f);
                    const float rB0 = fmaxf(cB[0], 0.f), rB1 = fmaxf(cB[1], 0.f);
                    const float rB2 = fmaxf(cB[2], 0.f), rB3 = fmaxf(cB[3], 0.f);
                    spA += ws[0] * rA0 + ws[1] * rA1 + ws[2] * rA2 + ws[3] * rA3;
                    spB += ws[0] * rB0 + ws[1] * rB1 + ws[2] * rB2 + ws[3] * rB3;
                    uint2 uA; uA.x = pk2(rA0, rA1); uA.y = pk2(rA2, rA3);
                    uint2 uB; uB.x = pk2(rB0, rB1); uB.y = pk2(rB2, rB3);
                    bh2A[mt] = __builtin_bit_cast(f16x4, uA);
                    bh2B[mt] = __builtin_bit_cast(f16x4, uB);
                }
                // ---- Wc layer (C = pd+bc) + FUSED rgb head, shared loads ----
                f32x4 accCA, accCB;
                #pragma unroll
                for (int mt = 0; mt < 4; ++mt) {
                    const int row = (16 * mt + lh) * 128;
                    const f16x4 a0 = *(const f16x4*)(sWc + row + (((0 + g) ^ swz8) << 3));
                    const f16x4 a1 = *(const f16x4*)(sWc + row + (((4 + g) ^ swz8) << 3));
                    const f16x4 a2 = *(const f16x4*)(sWc + row + (((8 + g) ^ swz8) << 3));
                    const f16x4 a3 = *(const f16x4*)(sWc + row + (((12 + g) ^ swz8) << 3));
                    const f32x4 pdf = *(const f32x4*)&sPdB[wid][16 * mt + 4 * g];
                    const f16x4 aC = *(const f16x4*)(sHC + lh * 128 + (((4 * mt + g) ^ swz8) << 3));
                    f32x4 cA = __builtin_amdgcn_mfma_f32_16x16x16f16(a0, bh2A[0], pdf, 0, 0, 0);
                    f32x4 cB = __builtin_amdgcn_mfma_f32_16x16x16f16(a0, bh2B[0], pdf, 0, 0, 0);
                    cA = __builtin_amdgcn_mfma_f32_16x16x16f16(a1, bh2A[1], cA, 0, 0, 0);
                    cB = __builtin_amdgcn_mfma_f32_16x16x16f16(a1, bh2B[1], cB, 0, 0, 0);
                    cA = __builtin_amdgcn_mfma_f32_16x16x16f16(a2, bh2A[2], cA, 0, 0, 0);
                    cB = __builtin_amdgcn_mfma_f32_16x16x16f16(a2, bh2B[2], cB, 0, 0, 0);
                    cA = __builtin_amdgcn_mfma_f32_16x16x16f16(a3, bh2A[3], cA, 0, 0, 0);
                    cB = __builtin_amdgcn_mfma_f32_16x16x16f16(a3, bh2B[3], cB, 0, 0, 0);
                    const f16x4 bgfA = pkh(cA);
                    const f16x4 bgfB = pkh(cB);
                    f32x4 caA = (mt == 0) ? f32x4{0.f, 0.f, 0.f, 0.f} : accCA;
                    f32x4 caB = (mt == 0) ? f32x4{0.f, 0.f, 0.f, 0.f} : accCB;
                    accCA = __builtin_amdgcn_mfma_f32_16x16x16f16(aC, bgfA, caA, 0, 0, 0);
                    accCB = __builtin_amdgcn_mfma_f32_16x16x16f16(aC, bgfB, caB, 0, 0, 0);
                }
                // ---- sigma reduce over g-groups ----
                spA += __shfl_xor(spA, 16);  spA += __shfl_xor(spA, 32);
                spB += __shfl_xor(spB, 16);  spB += __shfl_xor(spB, 32);
                // ---- rgb extraction: row 4g+j has color (g+j)%3 ----
                const float crA = (g == 1) ? accCA[2] : (g == 2) ? accCA[1] : accCA[0];
                const float cgA = (g == 0) ? accCA[1] : (g == 1) ? accCA[0]
                                : (g == 2) ? accCA[2] : accCA[1];
                const float cbA = (g == 0) ? accCA[2] : (g == 1) ? accCA[1]
                                : (g == 2) ? accCA[0] : accCA[2];
                const float crB = (g == 1) ? accCB[2] : (g == 2) ? accCB[1] : accCB[0];
                const float cgB = (g == 0) ? accCB[1] : (g == 1) ? accCB[0]
                                : (g == 2) ? accCB[2] : accCB[1];
                const float cbB = (g == 0) ? accCB[2] : (g == 1) ? accCB[1]
                                : (g == 2) ? accCB[0] : accCB[2];

                const float sigmaA = validA ? fmaxf(spA + bsV, 0.f) : 0.f;
                const float sigmaB = validB ? fmaxf(spB + bsV, 0.f) : 0.f;
                const float rCA = 1.f / (1.f + __expf(-(crA + br0)));
                const float gCA = 1.f / (1.f + __expf(-(cgA + br1)));
                const float bCA = 1.f / (1.f + __expf(-(cbA + br2)));
                const float rCB = 1.f / (1.f + __expf(-(crB + br0)));
                const float gCB = 1.f / (1.f + __expf(-(cgB + br1)));
                const float bCB = 1.f / (1.f + __expf(-(cbB + br2)));

                // ---- composite A then B (f-carry sequential, exact) ----
                const float sdA = sigmaA * STEPf;
                const float sdB = sigmaB * STEPf;
                float scA = sdA, scB = sdB;
                #pragma unroll
                for (int off = 1; off < 16; off <<= 1) {
                    const float nA = __shfl_up(scA, off);
                    const float nB = __shfl_up(scB, off);
                    if (lh >= off) { scA += nA; scB += nB; }
                }
                {
                    const float T = __expf(-(scA - sdA));
                    const float alpha = 1.f - __expf(-sdA);
                    const float w = f * T * alpha;
                    W += w; WT += w * tA; Rr += w * rCA; Gg += w * gCA; Bb += w * bCA;
                    f *= __expf(-rfl(__shfl(scA, (lane & 48) | 15)));
                }
                {
                    const float T = __expf(-(scB - sdB));
                    const float alpha = 1.f - __expf(-sdB);
                    const float w = f * T * alpha;
                    W += w; WT += w * tB; Rr += w * rCB; Gg += w * gCB; Bb += w * bCB;
                    f *= __expf(-rfl(__shfl(scB, (lane & 48) | 15)));
                }
            }

            if (__ballot(insegB) == 0ULL) break;   // nothing beyond this pair
            if (f < 6e-6f) break;                  // transmittance exhausted
        }
    }

    // ---- ONE reduce over the 16 lh lanes per ray (values g-replicated) ----
    #pragma unroll
    for (int off = 1; off < 16; off <<= 1) {
        W  += __shfl_xor(W,  off);
        WT += __shfl_xor(WT, off);
        Rr += __shfl_xor(Rr, off);
        Gg += __shfl_xor(Gg, off);
        Bb += __shfl_xor(Bb, off);
    }
    if (lane == 0) {
        const float bg_ = 1.f - W;
        out[ray * 3 + 0] = Rr + bg_;
        out[ray * 3 + 1] = Gg + bg_;
        out[ray * 3 + 2] = Bb + bg_;
        out[3 * nrays + ray] = WT;
        out[4 * nrays + ray] = W;
    }
}

extern "C" void kernel_launch(void* const* d_in, const int* in_sizes, int n_in,
                              void* d_out, int out_size, void* d_ws, size_t ws_size,
                              hipStream_t stream) {
    const float* rays_o   = (const float*)d_in[0];
    const float* viewdirs = (const float*)d_in[1];
    const void*  occ      = (const void*) d_in[2];
    const float* W1 = (const float*)d_in[3];
    const float* b1 = (const float*)d_in[4];
    const float* W2 = (const float*)d_in[5];
    const float* b2 = (const float*)d_in[6];
    const float* Ws = (const float*)d_in[7];
    const float* bs = (const float*)d_in[8];
    const float* Wc = (const float*)d_in[9];
    const float* Wd = (const float*)d_in[10];
    const float* bc = (const float*)d_in[11];
    const float* Wr = (const float*)d_in[12];
    const float* br = (const float*)d_in[13];
    float* out = (float*)d_out;

    const int nrays = in_sizes[0] / 3;
    const int nblocks = (nrays + 3) / 4;     // 4 rays (waves) per 256-thread block

    nerf_mfma<<<nblocks, 256, 0, stream>>>(rays_o, viewdirs, occ,
                                           W1, b1, W2, b2, Ws, bs, Wc, Wd, bc, Wr, br,
                                           out, nrays);
}

// Round 20
// 42.907 us; speedup vs baseline: 1.1577x; 1.1577x over previous
//
#include <hip/hip_runtime.h>
#include <math.h>

// NeRF fused volume renderer, MI355X (gfx950) — MFMA, independent-wave design.
// Round 20: REVERT to round-17 exactly (42.6us, session best).
//   Exploration record around this point: r15 gather-pipeline+setprio = null;
//   r18 clean-64 VGPR @ 24 waves/CU = -1.4us; r19 two-tile ILP = -7us (lost
//   per-tile empty-skip granularity + occupancy). r17's config — 512-thr
//   blocks, launch_bounds(512,8) (VGPR 32 + ~6MB L2-absorbed spill), 32
//   waves/CU peak, wave = whole ray walking 8x16-sample tiles sequentially,
//   scalarized wave-uniform setup, 6-register f-carry compositing, zero
//   main-loop barriers — is the empirical optimum of this design space.
// Layouts (m89-verified / ISA doc): C/D col=lane&15, row=(lane>>4)*4+reg;
// x32 A/B k=(lane>>4)*8+e; x16 A/B k=(lane>>4)*4+e.

typedef _Float16 f16x8 __attribute__((ext_vector_type(8)));
typedef _Float16 f16x4 __attribute__((ext_vector_type(4)));
typedef float f32x4 __attribute__((ext_vector_type(4)));

static constexpr float STEPf = 0.040594940802395566f; // 3*sqrt(3)/128 in f32

static __device__ __forceinline__ unsigned pk2(float a, float b) {
    return __builtin_bit_cast(unsigned, __builtin_amdgcn_cvt_pkrtz(a, b));
}
static __device__ __forceinline__ f16x8 mk8(unsigned a, unsigned b, unsigned c, unsigned d) {
    uint4 u = make_uint4(a, b, c, d);
    return __builtin_bit_cast(f16x8, u);
}
static __device__ __forceinline__ f16x4 pkh(const f32x4 c) {
    uint2 u;
    u.x = pk2(fmaxf(c[0], 0.f), fmaxf(c[1], 0.f));
    u.y = pk2(fmaxf(c[2], 0.f), fmaxf(c[3], 0.f));
    return __builtin_bit_cast(f16x4, u);
}
// force a wave-uniform f32 into an SGPR
static __device__ __forceinline__ float rfl(float x) {
    return __builtin_bit_cast(float, __builtin_amdgcn_readfirstlane(__builtin_bit_cast(int, x)));
}

extern "C" __global__ void __launch_bounds__(512, 8)
nerf_mfma(const float* __restrict__ rays_o, const float* __restrict__ viewdirs,
          const void* __restrict__ occ,
          const float* __restrict__ W1g, const float* __restrict__ b1g,
          const float* __restrict__ W2g, const float* __restrict__ b2g,
          const float* __restrict__ Wsg, const float* __restrict__ bsg,
          const float* __restrict__ Wcg, const float* __restrict__ Wdg,
          const float* __restrict__ bcg, const float* __restrict__ Wrg,
          const float* __restrict__ brg,
          float* __restrict__ out, int nrays)
{
    __shared__ __align__(16) unsigned char sW1[64 * 64];
    __shared__ __align__(16) unsigned char sW2[64 * 128];
    __shared__ __align__(16) unsigned char sWc[64 * 128];
    __shared__ __align__(16) unsigned char sHC[16 * 128];
    __shared__ __align__(16) float sWs[64];
    __shared__ __align__(16) float sB1[64], sB2[64];
    __shared__ __align__(16) float sPdB[8][64];    // per-wave (pe_d@Wd + bc); same-wave RW
    __shared__ int sKind;

    const int tid = threadIdx.x;   // 0..511

    // ---------------- staging: COALESCED global reads, swizzled LDS writes ----
    for (int idx = tid; idx < 1024; idx += 512)             // zero sW1 (covers k-pad)
        ((uint32_t*)sW1)[idx] = 0u;
    __syncthreads();                                        // pad-zero before scatter
    for (int idx = tid; idx < 27 * 64; idx += 512) {        // W1, linear in memory
        const int k = idx >> 6, h = idx & 63;
        *(_Float16*)(sW1 + h * 64 + (((k >> 3) ^ (h & 3)) << 4) + ((k & 7) << 1)) =
            (_Float16)W1g[idx];
    }
    for (int idx = tid; idx < 64 * 64; idx += 512) {        // W2, Wc, linear
        const int k = idx >> 6, h = idx & 63;
        const int off = h * 128 + ((((k >> 2) ^ ((h & 7) << 1)) << 3)) + ((k & 3) << 1);
        *(_Float16*)(sW2 + off) = (_Float16)W2g[idx];
        *(_Float16*)(sWc + off) = (_Float16)Wcg[idx];
    }
    for (int idx = tid; idx < 192; idx += 512) {            // rgb head rows, linear
        const int kk = idx / 3, c = idx - 3 * kk;
        const _Float16 v = (_Float16)Wrg[idx];
        #pragma unroll
        for (int r = 0; r < 16; ++r) {
            if ((r % 3) == c) {
                const int off = r * 128 + ((((kk >> 2) ^ ((r & 7) << 1)) << 3)) + ((kk & 3) << 1);
                *(_Float16*)(sHC + off) = v;
            }
        }
    }
    if (tid < 64) {
        sB1[tid] = b1g[tid]; sB2[tid] = b2g[tid];
        sWs[tid] = Wsg[tid];
    }
    if (tid == 0) {   // sniff occ dtype: 0=u8, else 32-bit raw (i32/f32 both !=0 test)
        const int*   oi = (const int*)occ;
        const float* of = (const float*)occ;
        bool i32ok = true, f32ok = true;
        for (int k = 0; k < 64; ++k) {
            if (oi[k] != 0 && oi[k] != 1) i32ok = false;
            const float f = of[k];
            if (!(f == 0.f || f == 1.f)) f32ok = false;
        }
        sKind = (i32ok || f32ok) ? 1 : 0;
    }
    __syncthreads();   // the ONLY block-wide barrier

    const int lane = tid & 63;
    const int wid  = tid >> 6;        // 0..7: wave = independent ray
    const int kind = sKind;
    const int lh = lane & 15, g = lane >> 4;
    const int swz8 = (lh & 7) << 1;

    const float bsV = bsg[0];
    const float br0 = brg[0], br1 = brg[1], br2 = brg[2];

    const int ray = __builtin_amdgcn_readfirstlane((int)(blockIdx.x << 3) + wid);
    if (ray >= nrays) return;

    // ---- per-ray setup; uniform scalars end in SGPRs (scalar loads + rfl) ----
    const float ox = rays_o[ray * 3 + 0], oy = rays_o[ray * 3 + 1], oz = rays_o[ray * 3 + 2];
    const float dxv = viewdirs[ray * 3 + 0], dyv = viewdirs[ray * 3 + 1], dzv = viewdirs[ray * 3 + 2];
    float t_near, t_far;
    {
        const float sdx = fabsf(dxv) < 1e-8f ? 1e-8f : dxv;
        const float sdy = fabsf(dyv) < 1e-8f ? 1e-8f : dyv;
        const float sdz = fabsf(dzv) < 1e-8f ? 1e-8f : dzv;
        const float t1x = (-1.5f - ox) / sdx, t2x = (1.5f - ox) / sdx;
        const float t1y = (-1.5f - oy) / sdy, t2y = (1.5f - oy) / sdy;
        const float t1z = (-1.5f - oz) / sdz, t2z = (1.5f - oz) / sdz;
        t_near = rfl(fmaxf(fmaxf(fminf(t1x, t2x), fminf(t1y, t2y)),
                           fmaxf(fminf(t1z, t2z), 0.f)));
        t_far  = rfl(fminf(fminf(fmaxf(t1x, t2x), fmaxf(t1y, t2y)), fmaxf(t1z, t2z)));
    }

    float W = 0.f, WT = 0.f, Rr = 0.f, Gg = 0.f, Bb = 0.f;

    if (t_near < t_far) {
        // dir posenc -> sPdB[wid] (lane j computes feature j; same-wave RW)
        {
            float ped[15];
            ped[0] = dxv; ped[1] = dyv; ped[2] = dzv;
            const float dc[3] = {dxv, dyv, dzv};
            #pragma unroll
            for (int c = 0; c < 3; ++c) {
                float s1, c1;
                __sincosf(dc[c], &s1, &c1);
                ped[3 + c * 4 + 0] = s1;
                ped[3 + c * 4 + 1] = 2.f * s1 * c1;
                ped[3 + c * 4 + 2] = c1;
                ped[3 + c * 4 + 3] = 1.f - 2.f * s1 * s1;
            }
            float pd = 0.f;
            #pragma unroll
            for (int i = 0; i < 15; ++i) pd += ped[i] * Wdg[i * 64 + lane];
            sPdB[wid][lane] = pd + bcg[lane];
        }

        float f = 1.f;
        #pragma unroll 1
        for (int bt = 0; bt < 8; ++bt) {
            const float tS = t_near + ((float)((bt << 4) | lh) + 0.5f) * STEPf;
            const bool in_seg = tS < t_far;
            if (__ballot(in_seg) == 0ULL) break;   // tiles ascend in t: done

            // ---- own-sample validity (occ gather) ----
            bool valid;
            {
                const float px = ox + dxv * tS, py = oy + dyv * tS, pz = oz + dzv * tS;
                const float cx = (px + 1.5f) * (128.f / 3.f);
                const float cy = (py + 1.5f) * (128.f / 3.f);
                const float cz = (pz + 1.5f) * (128.f / 3.f);
                const bool in_box = (cx >= 0.f) & (cx < 128.f) & (cy >= 0.f) & (cy < 128.f)
                                  & (cz >= 0.f) & (cz < 128.f);
                const int ix = min(max((int)floorf(cx), 0), 127);
                const int iy = min(max((int)floorf(cy), 0), 127);
                const int iz = min(max((int)floorf(cz), 0), 127);
                const int ci = (ix << 14) | (iy << 7) | iz;
                const unsigned raw = (kind == 0) ? (unsigned)((const unsigned char*)occ)[ci]
                                                 : ((const unsigned*)occ)[ci];
                valid = in_seg & in_box & (raw != 0u);
            }
            if (__ballot(valid) == 0ULL) continue;  // empty tile: S_tile = 0, f unchanged

            // ---- posenc in x32-B layout: lane -> feats 8g..8g+7 of sample lh ----
            f16x8 bx;
            {
                const float qx = ox + dxv * tS, qy = oy + dyv * tS, qz = oz + dzv * tS;
                const float u = (g < 2) ? qx : ((g == 2) ? qy : qz);
                const float v = (g == 1) ? qy : ((g == 2) ? qz : 0.f);
                float su1, cu1, sv1, cv1;
                __sincosf(u, &su1, &cu1);
                __sincosf(v, &sv1, &cv1);
                const float su2 = 2.f * su1 * cu1, cu2 = 1.f - 2.f * su1 * su1;
                const float su4 = 2.f * su2 * cu2, cu4 = 1.f - 2.f * su2 * su2;
                const float su8 = 2.f * su4 * cu4, cu8 = 1.f - 2.f * su4 * su4;
                const float sv2 = 2.f * sv1 * cv1, cv2 = 1.f - 2.f * sv1 * sv1;
                const float sv4 = 2.f * sv2 * cv2, cv4 = 1.f - 2.f * sv2 * sv2;
                const float sv8 = 2.f * sv4 * cv4;
                const bool g0 = (g == 0);
                const float f0 = g0 ? qx : cu2;
                const float f1 = g0 ? qy : cu4;
                const float f2 = g0 ? qz : cu8;
                const float f3 = g0 ? su1 : sv1;
                const float f4 = g0 ? su2 : sv2;
                const float f5 = g0 ? su4 : sv4;
                const float f6 = g0 ? su8 : sv8;
                const float f7 = g0 ? cu1 : ((g == 3) ? 0.f : cv1);
                bx = mk8(pk2(f0, f1), pk2(f2, f3), pk2(f4, f5), pk2(f6, f7));
            }

            // ---- L1 (16x16x32): bias as C ----
            f16x4 bh1[4];
            #pragma unroll
            for (int mt = 0; mt < 4; ++mt) {
                const f32x4 bf = *(const f32x4*)&sB1[16 * mt + 4 * g];
                const f16x8 a = *(const f16x8*)(sW1 + (16 * mt + lh) * 64 + ((g ^ (lh & 3)) << 4));
                f32x4 c = __builtin_amdgcn_mfma_f32_16x16x32_f16(a, bx, bf, 0, 0, 0);
                bh1[mt] = pkh(c);   // D rows 4g+r == B k 4g+e for k-step mt
            }
            // ---- L2 (4 x 16x16x16) + fused VALU sigma partial ----
            f16x4 bh2[4];
            float sp = 0.f;
            #pragma unroll
            for (int mt = 0; mt < 4; ++mt) {
                const int row = (16 * mt + lh) * 128;
                const f16x4 a0 = *(const f16x4*)(sW2 + row + (((0 + g) ^ swz8) << 3));
                const f16x4 a1 = *(const f16x4*)(sW2 + row + (((4 + g) ^ swz8) << 3));
                const f16x4 a2 = *(const f16x4*)(sW2 + row + (((8 + g) ^ swz8) << 3));
                const f16x4 a3 = *(const f16x4*)(sW2 + row + (((12 + g) ^ swz8) << 3));
                const f32x4 bf = *(const f32x4*)&sB2[16 * mt + 4 * g];
                const f32x4 ws = *(const f32x4*)&sWs[16 * mt + 4 * g];
                f32x4 c = __builtin_amdgcn_mfma_f32_16x16x16f16(a0, bh1[0], bf, 0, 0, 0);
                c = __builtin_amdgcn_mfma_f32_16x16x16f16(a1, bh1[1], c, 0, 0, 0);
                c = __builtin_amdgcn_mfma_f32_16x16x16f16(a2, bh1[2], c, 0, 0, 0);
                c = __builtin_amdgcn_mfma_f32_16x16x16f16(a3, bh1[3], c, 0, 0, 0);
                const float r0 = fmaxf(c[0], 0.f), r1 = fmaxf(c[1], 0.f);
                const float r2 = fmaxf(c[2], 0.f), r3 = fmaxf(c[3], 0.f);
                sp += ws[0] * r0 + ws[1] * r1 + ws[2] * r2 + ws[3] * r3;
                uint2 u; u.x = pk2(r0, r1); u.y = pk2(r2, r3);
                bh2[mt] = __builtin_bit_cast(f16x4, u);
            }
            // ---- Wc layer (C = pd + bc) + FUSED rgb head ----
            f32x4 accC;
            #pragma unroll
            for (int mt = 0; mt < 4; ++mt) {
                const int row = (16 * mt + lh) * 128;
                const f16x4 a0 = *(const f16x4*)(sWc + row + (((0 + g) ^ swz8) << 3));
                const f16x4 a1 = *(const f16x4*)(sWc + row + (((4 + g) ^ swz8) << 3));
                const f16x4 a2 = *(const f16x4*)(sWc + row + (((8 + g) ^ swz8) << 3));
                const f16x4 a3 = *(const f16x4*)(sWc + row + (((12 + g) ^ swz8) << 3));
                const f32x4 pdf = *(const f32x4*)&sPdB[wid][16 * mt + 4 * g];
                const f16x4 aC = *(const f16x4*)(sHC + lh * 128 + (((4 * mt + g) ^ swz8) << 3));
                f32x4 c = __builtin_amdgcn_mfma_f32_16x16x16f16(a0, bh2[0], pdf, 0, 0, 0);
                c = __builtin_amdgcn_mfma_f32_16x16x16f16(a1, bh2[1], c, 0, 0, 0);
                c = __builtin_amdgcn_mfma_f32_16x16x16f16(a2, bh2[2], c, 0, 0, 0);
                c = __builtin_amdgcn_mfma_f32_16x16x16f16(a3, bh2[3], c, 0, 0, 0);
                const f16x4 bgf = pkh(c);
                f32x4 ca = (mt == 0) ? f32x4{0.f, 0.f, 0.f, 0.f} : accC;
                accC = __builtin_amdgcn_mfma_f32_16x16x16f16(aC, bgf, ca, 0, 0, 0);
            }
            // ---- sigma reduce over g-groups (all lanes get full sum) ----
            sp += __shfl_xor(sp, 16);
            sp += __shfl_xor(sp, 32);
            // ---- rgb extraction: row 4g+j has color (g+j)%3 ----
            const float crS = (g == 1) ? accC[2] : (g == 2) ? accC[1] : accC[0];
            const float cgS = (g == 0) ? accC[1] : (g == 1) ? accC[0]
                            : (g == 2) ? accC[2] : accC[1];
            const float cbS = (g == 0) ? accC[2] : (g == 1) ? accC[1]
                            : (g == 2) ? accC[0] : accC[2];

            const float sigma = valid ? fmaxf(sp + bsV, 0.f) : 0.f;
            const float rC = 1.f / (1.f + __expf(-(crS + br0)));
            const float gC = 1.f / (1.f + __expf(-(cgS + br1)));
            const float bC = 1.f / (1.f + __expf(-(cbS + br2)));

            // ---- compositing over this tile (carry via f, exact) ----
            const float sdelta = sigma * STEPf;
            float scan = sdelta;
            #pragma unroll
            for (int off = 1; off < 16; off <<= 1) {
                const float n = __shfl_up(scan, off);
                if (lh >= off) scan += n;
            }
            const float T     = __expf(-(scan - sdelta));
            const float alpha = 1.f - __expf(-sdelta);
            const float w = f * T * alpha;          // tile factor folded per-lane
            W  += w;
            WT += w * tS;
            Rr += w * rC;
            Gg += w * gC;
            Bb += w * bC;
            const float Stile = rfl(__shfl(scan, (lane & 48) | 15));  // tile sigma-sum
            f *= __expf(-Stile);
            if (f < 6e-6f) break;                   // transmittance exhausted
        }
    }

    // ---- ONE reduce over the 16 lh lanes per ray (values g-replicated) ----
    #pragma unroll
    for (int off = 1; off < 16; off <<= 1) {
        W  += __shfl_xor(W,  off);
        WT += __shfl_xor(WT, off);
        Rr += __shfl_xor(Rr, off);
        Gg += __shfl_xor(Gg, off);
        Bb += __shfl_xor(Bb, off);
    }
    if (lane == 0) {
        const float bg_ = 1.f - W;
        out[ray * 3 + 0] = Rr + bg_;
        out[ray * 3 + 1] = Gg + bg_;
        out[ray * 3 + 2] = Bb + bg_;
        out[3 * nrays + ray] = WT;
        out[4 * nrays + ray] = W;
    }
}

extern "C" void kernel_launch(void* const* d_in, const int* in_sizes, int n_in,
                              void* d_out, int out_size, void* d_ws, size_t ws_size,
                              hipStream_t stream) {
    const float* rays_o   = (const float*)d_in[0];
    const float* viewdirs = (const float*)d_in[1];
    const void*  occ      = (const void*) d_in[2];
    const float* W1 = (const float*)d_in[3];
    const float* b1 = (const float*)d_in[4];
    const float* W2 = (const float*)d_in[5];
    const float* b2 = (const float*)d_in[6];
    const float* Ws = (const float*)d_in[7];
    const float* bs = (const float*)d_in[8];
    const float* Wc = (const float*)d_in[9];
    const float* Wd = (const float*)d_in[10];
    const float* bc = (const float*)d_in[11];
    const float* Wr = (const float*)d_in[12];
    const float* br = (const float*)d_in[13];
    float* out = (float*)d_out;

    const int nrays = in_sizes[0] / 3;
    const int nblocks = (nrays + 7) / 8;     // 8 rays (waves) per 512-thread block
                                             // nrays=8192 -> 1024 = whole grid resident

    nerf_mfma<<<nblocks, 512, 0, stream>>>(rays_o, viewdirs, occ,
                                           W1, b1, W2, b2, Ws, bs, Wc, Wd, bc, Wr, br,
                                           out, nrays);
}